// Round 13
// baseline (275.602 us; speedup 1.0000x reference)
//
#include <hip/hip_runtime.h>
#include <hip/hip_bf16.h>

#define B_SZ 16
#define IN_C 64
#define OUT_C 64
#define STYLE_DIM 512
#define HW 16384          // 128*128
#define EPS 1e-8f

// ---------------------------------------------------------------------------
// Kernel 1: modulated+demodulated weight, stored TRANSPOSED: WT[b][i][o].
// 16 blocks x 256 threads, ~3us. (Math identical to R12's verified phase1/2.)
// ---------------------------------------------------------------------------
__global__ __launch_bounds__(256) void modw_kernel(
    const float* __restrict__ style,   // (B, STYLE_DIM)
    const float* __restrict__ weight,  // (OUT_C, IN_C)
    const float* __restrict__ geo_w,   // (IN_C, STYLE_DIM)
    const float* __restrict__ geo_b,   // (IN_C)
    float* __restrict__ WT)            // (B, IN_C, OUT_C)
{
    const int b   = blockIdx.x;
    const int tid = threadIdx.x;
    __shared__ float smod[IN_C];

    {   // smod[i] = dot(style[b], geo_w[i]) + geo_b[i] + 1
        const int i    = tid >> 2;
        const int part = tid & 3;
        const float4* st4 = reinterpret_cast<const float4*>(style + b * STYLE_DIM + part * 128);
        const float4* gw4 = reinterpret_cast<const float4*>(geo_w + i * STYLE_DIM + part * 128);
        float s = 0.0f;
        #pragma unroll
        for (int k = 0; k < 32; ++k) {
            const float4 a = st4[k];
            const float4 g = gw4[k];
            s = fmaf(a.x, g.x, s); s = fmaf(a.y, g.y, s);
            s = fmaf(a.z, g.z, s); s = fmaf(a.w, g.w, s);
        }
        s += __shfl_xor(s, 1);
        s += __shfl_xor(s, 2);
        if (part == 0) smod[i] = s + geo_b[i] + 1.0f;
    }
    __syncthreads();

    {   // demod + transposed store; 4 threads per o
        const int o    = tid >> 2;
        const int part = tid & 3;
        const float* wr = weight + o * IN_C + part * 16;
        const float* sm = smod + part * 16;
        float wv[16];
        float d = 0.0f;
        #pragma unroll
        for (int k = 0; k < 16; ++k) {
            wv[k] = wr[k] * sm[k];
            d = fmaf(wv[k], wv[k], d);
        }
        d += __shfl_xor(d, 1);
        d += __shfl_xor(d, 2);
        d = rsqrtf(d + EPS);
        #pragma unroll
        for (int k = 0; k < 16; ++k)
            WT[(b << 12) + (part * 16 + k) * OUT_C + o] = wv[k] * d;
    }
}

// ---------------------------------------------------------------------------
// Kernel 2 (hot): out[b][o][hw] = sum_i WT[b][i][o] * x[b][i][hw] + bias[o]
//
// R7-R12 post-mortem: every LDS/barrier-staged variant stalled at 82-105us
// with ~6 waves/CU effective. This version follows the guide's memory-bound
// recipe instead (m219/m238: high TLP, no barriers): NO LDS, NO barriers,
// 2048 blocks x 256 threads. Wave w owns 16 out-channels (og uniform via
// readfirstlane -> W loads scalarize to s_load on the SMEM pipe, v_fmac
// reads them as the 1 allowed SGPR operand). Lane owns 2 hw (float2 loads,
// depth-2 rolling prefetch). acc=32 VGPR -> 6-8 waves/SIMD resident.
// x: each line HBM-fetched once (4 og-waves dedupe in L1/L2).
// ---------------------------------------------------------------------------
__global__ __launch_bounds__(256, 6) void conv_kernel(
    const float* __restrict__ x,     // (B, IN_C, HW)
    const float* __restrict__ WT,    // (B, IN_C, OUT_C)
    const float* __restrict__ bias,  // (OUT_C)
    float* __restrict__ out)         // (B, OUT_C, HW)
{
    const int tid  = threadIdx.x;
    const int b    = blockIdx.x >> 7;             // 128 tiles per sample
    const int hw0  = (blockIdx.x & 127) << 7;     // 128 hw per block
    const int lane = tid & 63;
    int og = (tid >> 6) << 4;                     // 0,16,32,48 (wave-uniform)
    og = __builtin_amdgcn_readfirstlane(og);

    const float* wrow = WT + (b << 12) + og;      // + i*64 + o  (uniform)
    const float* xb   = x + (size_t)(b << 6) * HW + hw0 + (lane << 1);

    float2 acc[16];
    #pragma unroll
    for (int o = 0; o < 16; ++o) acc[o] = make_float2(0.0f, 0.0f);

    // depth-2 rolling prefetch of x
    float2 x0 = *reinterpret_cast<const float2*>(xb);
    float2 x1 = *reinterpret_cast<const float2*>(xb + HW);

    #pragma unroll
    for (int i = 0; i < IN_C; ++i) {
        float2 xn = x1;
        if (i + 2 < IN_C)
            xn = *reinterpret_cast<const float2*>(xb + (size_t)(i + 2) * HW);
        const float* wr = wrow + (i << 6);
        #pragma unroll
        for (int o = 0; o < 16; ++o) {
            const float w = wr[o];                // uniform -> s_load
            acc[o].x = fmaf(w, x0.x, acc[o].x);
            acc[o].y = fmaf(w, x0.y, acc[o].y);
        }
        x0 = x1; x1 = xn;
    }

    float* ob = out + (size_t)((b << 6) + og) * HW + hw0 + (lane << 1);
    #pragma unroll
    for (int o = 0; o < 16; ++o) {
        const float bv = bias[og + o];
        const float2 r = make_float2(acc[o].x + bv, acc[o].y + bv);
        *reinterpret_cast<float2*>(ob + (size_t)o * HW) = r;
    }
}

extern "C" void kernel_launch(void* const* d_in, const int* in_sizes, int n_in,
                              void* d_out, int out_size, void* d_ws, size_t ws_size,
                              hipStream_t stream) {
    const float* x      = (const float*)d_in[0];  // (16,64,128,128)
    const float* style  = (const float*)d_in[1];  // (16,512)
    const float* weight = (const float*)d_in[2];  // (1,64,64,1,1)
    const float* bias   = (const float*)d_in[3];  // (1,64)
    const float* geo_w  = (const float*)d_in[4];  // (64,512)
    const float* geo_b  = (const float*)d_in[5];  // (64)
    float* out = (float*)d_out;
    float* WT  = (float*)d_ws;                    // 16*64*64*4 = 64 KB

    modw_kernel<<<B_SZ, 256, 0, stream>>>(style, weight, geo_w, geo_b, WT);
    conv_kernel<<<B_SZ * (HW / 128), 256, 0, stream>>>(x, WT, bias, out);
}